// Round 9
// baseline (313.845 us; speedup 1.0000x reference)
//
#include <hip/hip_runtime.h>
#include <hip/hip_bf16.h>
#include <math.h>

#define NN 100000
#define NE 1600000
#define ET (NE + NN)
#define CIN 128
#define H1 4
#define C1 32
#define HC1 128
#define C2 64
#define NEG 0.2f
#define NB1 196          // ceil(NN/512) coarse buckets (512 nodes each)
#define SBLK 256         // scatter blocks
#define ECHUNK ((NE + SBLK - 1) / SBLK)  // 6250 edges per scatter block
#define BCAP 12288       // bucket LDS capacity (entries); expected max ~9500

typedef __attribute__((ext_vector_type(8))) short short8v;
typedef __attribute__((ext_vector_type(4))) float f32x4;

__device__ __forceinline__ float bfu2f(unsigned short u) {
  union { unsigned u; float f; } c; c.u = ((unsigned)u) << 16; return c.f;
}
__device__ __forceinline__ float bflo(unsigned v) {
  union { unsigned u; float f; } c; c.u = v << 16; return c.f;
}
__device__ __forceinline__ float bfhi(unsigned v) {
  union { unsigned u; float f; } c; c.u = v & 0xffff0000u; return c.f;
}
__device__ __forceinline__ unsigned short f2bfu(float f) {
  union { __hip_bfloat16 b; unsigned short u; } c; c.b = __float2bfloat16(f); return c.u;
}

// ---- dtype probe: are the float inputs bf16 or f32? ----
__global__ void k_detect(const unsigned short* __restrict__ x, int* __restrict__ flag) {
  __shared__ int cnt;
  if (threadIdx.x == 0) cnt = 0;
  __syncthreads();
  int bad = 0;
  for (int i = threadIdx.x; i < 2048; i += 256) {
    unsigned short u = x[i];
    int ex = (u >> 7) & 0xFF;
    bool ok = ((u & 0x7FFF) == 0) || (ex >= 90 && ex <= 140);
    if (!ok) bad++;
  }
  atomicAdd(&cnt, bad);
  __syncthreads();
  if (threadIdx.x == 0) *flag = (cnt * 10 < 2048) ? 1 : 0;  // 1 = bf16
}

// merged param conversion: W1->bf16, W2->bf16, att/bias->f32
__global__ void k_params(const void* __restrict__ W1, const void* __restrict__ W2,
                         const void* as1, const void* ad1, const void* b1,
                         const void* as2, const void* ad2, const void* b2,
                         unsigned short* __restrict__ W1b, unsigned short* __restrict__ W2b,
                         float* pAS1, float* pAD1, float* b1f,
                         float* pAS2, float* pAD2, float* b2f,
                         const int* __restrict__ flag) {
  int g = blockIdx.x * 256 + threadIdx.x;
  int isbf = *flag;
  auto cv = [&](const void* p, int idx) -> float {
    return isbf ? bfu2f(((const unsigned short*)p)[idx]) : ((const float*)p)[idx];
  };
  if (g < CIN * HC1) {
    W1b[g] = isbf ? ((const unsigned short*)W1)[g] : f2bfu(((const float*)W1)[g]);
  } else if (g < CIN * HC1 + HC1 * C2) {
    int i = g - CIN * HC1;
    W2b[i] = isbf ? ((const unsigned short*)W2)[i] : f2bfu(((const float*)W2)[i]);
  } else {
    int i = g - (CIN * HC1 + HC1 * C2);
    if (i < HC1) { pAS1[i] = cv(as1, i); pAD1[i] = cv(ad1, i); b1f[i] = cv(b1, i); }
    else if (i < HC1 + C2) {
      int j = i - HC1;
      pAS2[j] = cv(as2, j); pAD2[j] = cv(ad2, j); b2f[j] = cv(b2, j);
    }
  }
}

// ================= CSR build: dense counting sort, no global atomics ========
__global__ __launch_bounds__(256) void k_histo(
    const int* __restrict__ dst, int* __restrict__ gcnt) {
  __shared__ int hist[NB1];
  for (int b = threadIdx.x; b < NB1; b += 256) hist[b] = 0;
  __syncthreads();
  int e0 = blockIdx.x * ECHUNK;
  int e1 = min(e0 + ECHUNK, NE);
  for (int e = e0 + threadIdx.x; e < e1; e += 256)
    atomicAdd(&hist[dst[e] >> 9], 1);
  __syncthreads();
  for (int b = threadIdx.x; b < NB1; b += 256)
    gcnt[b * SBLK + blockIdx.x] = hist[b];
}

__global__ void k_histscan(int* __restrict__ gcnt, int* __restrict__ bucketReal) {
  __shared__ int sm[SBLK];
  int b = blockIdx.x;
  int t = threadIdx.x;
  int v = gcnt[b * SBLK + t];
  sm[t] = v;
  __syncthreads();
  for (int off = 1; off < SBLK; off <<= 1) {
    int tmp = (t >= off) ? sm[t - off] : 0;
    __syncthreads();
    sm[t] += tmp;
    __syncthreads();
  }
  gcnt[b * SBLK + t] = sm[t] - v;  // exclusive
  if (t == SBLK - 1) bucketReal[b] = sm[SBLK - 1];
}

__global__ void k_base(const int* __restrict__ bucketReal, int* __restrict__ sBase,
                       int* __restrict__ rowptr) {
  __shared__ int sm[256];
  int t = threadIdx.x;
  int v = (t < NB1) ? bucketReal[t] : 0;
  sm[t] = v;
  __syncthreads();
  for (int off = 1; off < 256; off <<= 1) {
    int tmp = (t >= off) ? sm[t - off] : 0;
    __syncthreads();
    sm[t] += tmp;
    __syncthreads();
  }
  if (t < NB1) sBase[t] = sm[t] - v;  // exclusive (real edges only)
  if (t == 0) rowptr[NN] = ET;
}

// scatter packed (src | dstLow<<17) into bucket-major staging; dense-run writes
__global__ __launch_bounds__(256) void k_scatter(
    const int* __restrict__ src, const int* __restrict__ dst,
    const int* __restrict__ gcnt, const int* __restrict__ sBase,
    unsigned* __restrict__ staging) {
  __shared__ int lcur[NB1];
  for (int b = threadIdx.x; b < NB1; b += 256)
    lcur[b] = sBase[b] + gcnt[b * SBLK + blockIdx.x];
  __syncthreads();
  int e0 = blockIdx.x * ECHUNK;
  int e1 = min(e0 + ECHUNK, NE);
  for (int e = e0 + threadIdx.x; e < e1; e += 256) {
    int s = src[e], d = dst[e];
    int pos = atomicAdd(&lcur[d >> 9], 1);
    staging[pos] = (unsigned)s | ((unsigned)(d & 511) << 17);
  }
}

// per-bucket: node histogram -> scan -> rowptr + sorted col (LDS staged)
__global__ __launch_bounds__(256) void k_bucket(
    const unsigned* __restrict__ staging, const int* __restrict__ sBase,
    const int* __restrict__ bucketReal, int* __restrict__ rowptr,
    int* __restrict__ col) {
  __shared__ int lhist[512];
  __shared__ int lcol[BCAP];
  __shared__ int ps[256];
  int b = blockIdx.x;
  int t = threadIdx.x;
  int n0 = b << 9;
  int nc = min(512, NN - n0);
  int sb = sBase[b];
  int realE = bucketReal[b];
  int regionStart = sb + n0;  // prior buckets each contribute 512 self-loops
  int total = realE + nc;
  lhist[t] = (t < nc) ? 1 : 0;            // self-loop
  lhist[t + 256] = (t + 256 < nc) ? 1 : 0;
  __syncthreads();
  for (int i = t; i < realE; i += 256)
    atomicAdd(&lhist[staging[sb + i] >> 17], 1);
  __syncthreads();
  // exclusive scan of 512 counters
  int v0 = lhist[t * 2], v1 = lhist[t * 2 + 1];
  int run = v0 + v1;
  ps[t] = run;
  __syncthreads();
  for (int off = 1; off < 256; off <<= 1) {
    int tmp = (t >= off) ? ps[t - off] : 0;
    __syncthreads();
    ps[t] += tmp;
    __syncthreads();
  }
  int base = ps[t] - run;
  lhist[t * 2] = base;
  lhist[t * 2 + 1] = base + v0;
  __syncthreads();
  // rowptr (before cursors mutate)
  for (int i = t; i < nc; i += 256)
    rowptr[n0 + i] = regionStart + lhist[i];
  __syncthreads();
  // self-loops first, then real edges
  for (int i = t; i < nc; i += 256) {
    int r = atomicAdd(&lhist[i], 1);
    if (r < BCAP) lcol[r] = n0 + i;
    else col[regionStart + r] = n0 + i;
  }
  for (int i = t; i < realE; i += 256) {
    unsigned p = staging[sb + i];
    int r = atomicAdd(&lhist[p >> 17], 1);
    int sv = (int)(p & 0x1FFFFu);
    if (r < BCAP) lcol[r] = sv;
    else col[regionStart + r] = sv;
  }
  __syncthreads();
  int lim = min(total, BCAP);
  for (int i = t; i < lim; i += 256)
    col[regionStart + i] = lcol[i];
}

// ================= bf16 MFMA GEMM + fused attention dots =================
// HEADMAJOR: C written as per-head planes Cb[h][M][C], ns/nd head-major.
template<int NT, int H, bool MAYBE_F32, bool HEADMAJOR>
__global__ __launch_bounds__(256) void k_gemm_mfma(
    const void* __restrict__ Araw, const unsigned short* __restrict__ W,
    unsigned short* __restrict__ Cb, const float* __restrict__ attS,
    const float* __restrict__ attD, float* __restrict__ ns,
    float* __restrict__ nd, int M, const int* __restrict__ flag) {
  constexpr int NC = NT * 16;
  constexpr int C = NC / H;
  __shared__ __align__(16) unsigned short lds[NC * 128];
  int t = threadIdx.x;
#pragma unroll
  for (int r = 0; r < (128 * NC) / (256 * 8); ++r) {
    int f = (t + r * 256) * 8;
    int k = f / NC;
    int n0 = f - k * NC;  // multiple of 8
    short8v v = *(const short8v*)(W + k * NC + n0);
#pragma unroll
    for (int j = 0; j < 8; ++j) {
      int n = n0 + j;
      lds[n * 128 + (((k >> 3) ^ (n & 7)) << 3) + (k & 7)] = ((const unsigned short*)&v)[j];
    }
  }
  __syncthreads();
  int wave = t >> 6, lane = t & 63;
  int m0 = (blockIdx.x * 4 + wave) * 32;
  if (m0 >= M) return;
  int isbf = MAYBE_F32 ? *flag : 1;
  f32x4 acc[2][NT];
#pragma unroll
  for (int mt = 0; mt < 2; ++mt)
#pragma unroll
    for (int nt = 0; nt < NT; ++nt) acc[mt][nt] = (f32x4)(0.f);
  int r0 = m0 + (lane & 15);
  int koff = (lane >> 4) << 3;
#pragma unroll
  for (int ks = 0; ks < 4; ++ks) {
    short8v af0, af1;
    if (isbf) {
      const unsigned short* A = (const unsigned short*)Araw;
      af0 = *(const short8v*)(A + (size_t)r0 * 128 + koff + ks * 32);
      af1 = *(const short8v*)(A + (size_t)(r0 + 16) * 128 + koff + ks * 32);
    } else {
      const float* A = (const float*)Araw;
      const float* p0 = A + (size_t)r0 * 128 + koff + ks * 32;
      const float* p1 = A + (size_t)(r0 + 16) * 128 + koff + ks * 32;
      float4 u0 = *(const float4*)p0, u1 = *(const float4*)(p0 + 4);
      float4 v0 = *(const float4*)p1, v1 = *(const float4*)(p1 + 4);
      unsigned short* a0 = (unsigned short*)&af0;
      unsigned short* a1 = (unsigned short*)&af1;
      a0[0] = f2bfu(u0.x); a0[1] = f2bfu(u0.y); a0[2] = f2bfu(u0.z); a0[3] = f2bfu(u0.w);
      a0[4] = f2bfu(u1.x); a0[5] = f2bfu(u1.y); a0[6] = f2bfu(u1.z); a0[7] = f2bfu(u1.w);
      a1[0] = f2bfu(v0.x); a1[1] = f2bfu(v0.y); a1[2] = f2bfu(v0.z); a1[3] = f2bfu(v0.w);
      a1[4] = f2bfu(v1.x); a1[5] = f2bfu(v1.y); a1[6] = f2bfu(v1.z); a1[7] = f2bfu(v1.w);
    }
#pragma unroll
    for (int nt = 0; nt < NT; ++nt) {
      int n = nt * 16 + (lane & 15);
      int chunk = ks * 4 + (lane >> 4);
      short8v bf = *(const short8v*)&lds[n * 128 + ((chunk ^ (n & 7)) << 3)];
      acc[0][nt] = __builtin_amdgcn_mfma_f32_16x16x32_bf16(af0, bf, acc[0][nt], 0, 0, 0);
      acc[1][nt] = __builtin_amdgcn_mfma_f32_16x16x32_bf16(af1, bf, acc[1][nt], 0, 0, 0);
    }
  }
  constexpr int NPH = NT / H;
#pragma unroll
  for (int mt = 0; mt < 2; ++mt) {
    int mb = m0 + mt * 16;
#pragma unroll
    for (int nt = 0; nt < NT; ++nt)
#pragma unroll
      for (int r = 0; r < 4; ++r) {
        int row = mb + ((lane >> 4) << 2) + r;
        int ch = nt * 16 + (lane & 15);
        if (HEADMAJOR) {
          int h = ch / C, c = ch % C;
          Cb[(size_t)h * M * C + (size_t)row * C + c] = f2bfu(acc[mt][nt][r]);
        } else {
          Cb[(size_t)row * NC + ch] = f2bfu(acc[mt][nt][r]);
        }
      }
#pragma unroll
    for (int r = 0; r < 4; ++r) {
      int row = mb + ((lane >> 4) << 2) + r;
#pragma unroll
      for (int h = 0; h < H; ++h) {
        float ps = 0.f, pd = 0.f;
#pragma unroll
        for (int q = 0; q < NPH; ++q) {
          int nt = h * NPH + q;
          int ch = nt * 16 + (lane & 15);
          ps = fmaf(acc[mt][nt][r], attS[ch], ps);
          pd = fmaf(acc[mt][nt][r], attD[ch], pd);
        }
#pragma unroll
        for (int off = 8; off; off >>= 1) {
          ps += __shfl_xor(ps, off);
          pd += __shfl_xor(pd, off);
        }
        if ((lane & 15) == 0) {
          if (HEADMAJOR) { ns[(size_t)h * M + row] = ps; nd[(size_t)h * M + row] = pd; }
          else { ns[row * H + h] = ps; nd[row * H + h] = pd; }
        }
      }
    }
  }
}

// ====== layer-1 aggregation: head-split, XCD-pinned, 64 B/edge gather ======
// grid = 12500*8; h = (bid&7)>>1 (head pinned to XCD pair), 4 nodes/block.
__global__ __launch_bounds__(256) void k_agg1h(
    const int* __restrict__ rowptr, const int* __restrict__ col,
    const float* __restrict__ nsh, const float* __restrict__ ndh,
    const unsigned short* __restrict__ xph, const float* __restrict__ bias,
    unsigned short* __restrict__ hb) {
  constexpr int LPE = 4, EPW = 16, CPL = 8;
  int wave = threadIdx.x >> 6;
  int lane = threadIdx.x & 63;
  int b7 = blockIdx.x & 7;
  int h = b7 >> 1;
  int i = ((blockIdx.x >> 3) << 1) + (b7 & 1);
  int n = i * 4 + wave;
  if (n >= NN) return;
  int rs = rowptr[n];
  int deg = rowptr[n + 1] - rs;
  int le = lane & (LPE - 1);
  int eg = lane >> 2;
  int ch0 = le * CPL;
  const float* nsp = nsh + (size_t)h * NN;
  float ndv = ndh[(size_t)h * NN + n];
  const unsigned short* xpb = xph + (size_t)h * NN * C1 + ch0;
  float den = 0.f;
  float acc[CPL];
#pragma unroll
  for (int c = 0; c < CPL; ++c) acc[c] = 0.f;
  int j = eg;
  for (; j + EPW < deg; j += 2 * EPW) {
    int s0 = col[rs + j], s1 = col[rs + j + EPW];
    float l0 = nsp[s0] + ndv, l1 = nsp[s1] + ndv;
    l0 = l0 >= 0.f ? l0 : NEG * l0;
    l1 = l1 >= 0.f ? l1 : NEG * l1;
    float w0 = __expf(l0), w1 = __expf(l1);
    den += w0 + w1;
    uint4 v0 = *(const uint4*)(xpb + (size_t)s0 * C1);
    uint4 v1 = *(const uint4*)(xpb + (size_t)s1 * C1);
    acc[0] = fmaf(w0, bflo(v0.x), acc[0]); acc[1] = fmaf(w0, bfhi(v0.x), acc[1]);
    acc[2] = fmaf(w0, bflo(v0.y), acc[2]); acc[3] = fmaf(w0, bfhi(v0.y), acc[3]);
    acc[4] = fmaf(w0, bflo(v0.z), acc[4]); acc[5] = fmaf(w0, bfhi(v0.z), acc[5]);
    acc[6] = fmaf(w0, bflo(v0.w), acc[6]); acc[7] = fmaf(w0, bfhi(v0.w), acc[7]);
    acc[0] = fmaf(w1, bflo(v1.x), acc[0]); acc[1] = fmaf(w1, bfhi(v1.x), acc[1]);
    acc[2] = fmaf(w1, bflo(v1.y), acc[2]); acc[3] = fmaf(w1, bfhi(v1.y), acc[3]);
    acc[4] = fmaf(w1, bflo(v1.z), acc[4]); acc[5] = fmaf(w1, bfhi(v1.z), acc[5]);
    acc[6] = fmaf(w1, bflo(v1.w), acc[6]); acc[7] = fmaf(w1, bfhi(v1.w), acc[7]);
  }
  if (j < deg) {
    int s = col[rs + j];
    float l = nsp[s] + ndv;
    l = l >= 0.f ? l : NEG * l;
    float w = __expf(l);
    den += w;
    uint4 v = *(const uint4*)(xpb + (size_t)s * C1);
    acc[0] = fmaf(w, bflo(v.x), acc[0]); acc[1] = fmaf(w, bfhi(v.x), acc[1]);
    acc[2] = fmaf(w, bflo(v.y), acc[2]); acc[3] = fmaf(w, bfhi(v.y), acc[3]);
    acc[4] = fmaf(w, bflo(v.z), acc[4]); acc[5] = fmaf(w, bfhi(v.z), acc[5]);
    acc[6] = fmaf(w, bflo(v.w), acc[6]); acc[7] = fmaf(w, bfhi(v.w), acc[7]);
  }
#pragma unroll
  for (int off = 32; off >= LPE; off >>= 1) {
    den += __shfl_xor(den, off);
#pragma unroll
    for (int c = 0; c < CPL; ++c) acc[c] += __shfl_xor(acc[c], off);
  }
  if (eg != 0) return;
  float inv = 1.f / den;
  float o[CPL];
#pragma unroll
  for (int c = 0; c < CPL; ++c) {
    o[c] = acc[c] * inv + bias[h * C1 + ch0 + c];
    o[c] = o[c] > 0.f ? o[c] : __expf(o[c]) - 1.f;  // ELU
  }
  uint4 pk;
  pk.x = (unsigned)f2bfu(o[0]) | ((unsigned)f2bfu(o[1]) << 16);
  pk.y = (unsigned)f2bfu(o[2]) | ((unsigned)f2bfu(o[3]) << 16);
  pk.z = (unsigned)f2bfu(o[4]) | ((unsigned)f2bfu(o[5]) << 16);
  pk.w = (unsigned)f2bfu(o[6]) | ((unsigned)f2bfu(o[7]) << 16);
  *(uint4*)(hb + (size_t)n * HC1 + h * C1 + ch0) = pk;
}

// ====== layer-2 aggregation (H=1), edge-transposed, unchanged structure =====
__global__ __launch_bounds__(256) void k_agg2(
    const int* __restrict__ rowptr, const int* __restrict__ col,
    const float* __restrict__ ns, const float* __restrict__ nd,
    const unsigned short* __restrict__ xp, const float* __restrict__ bias,
    void* __restrict__ outp, const int* __restrict__ flag) {
  constexpr int HC = C2, LPE = 8, CPL = 8, EPW = 8;
  int wave = threadIdx.x >> 6;
  int lane = threadIdx.x & 63;
  int n = blockIdx.x * 4 + wave;
  if (n >= NN) return;
  int rs = rowptr[n];
  int deg = rowptr[n + 1] - rs;
  int le = lane & (LPE - 1);
  int eg = lane / LPE;
  int ch0 = le * CPL;
  float ndv = nd[n];
  const unsigned short* xpc = xp + ch0;
  float den = 0.f;
  float acc[CPL];
#pragma unroll
  for (int c = 0; c < CPL; ++c) acc[c] = 0.f;
  int j = eg;
  for (; j + EPW < deg; j += 2 * EPW) {
    int s0 = col[rs + j], s1 = col[rs + j + EPW];
    float l0 = ns[s0] + ndv, l1 = ns[s1] + ndv;
    l0 = l0 >= 0.f ? l0 : NEG * l0;
    l1 = l1 >= 0.f ? l1 : NEG * l1;
    float w0 = __expf(l0), w1 = __expf(l1);
    den += w0 + w1;
    uint4 v0 = *(const uint4*)(xpc + (size_t)s0 * HC);
    uint4 v1 = *(const uint4*)(xpc + (size_t)s1 * HC);
    acc[0] = fmaf(w0, bflo(v0.x), acc[0]); acc[1] = fmaf(w0, bfhi(v0.x), acc[1]);
    acc[2] = fmaf(w0, bflo(v0.y), acc[2]); acc[3] = fmaf(w0, bfhi(v0.y), acc[3]);
    acc[4] = fmaf(w0, bflo(v0.z), acc[4]); acc[5] = fmaf(w0, bfhi(v0.z), acc[5]);
    acc[6] = fmaf(w0, bflo(v0.w), acc[6]); acc[7] = fmaf(w0, bfhi(v0.w), acc[7]);
    acc[0] = fmaf(w1, bflo(v1.x), acc[0]); acc[1] = fmaf(w1, bfhi(v1.x), acc[1]);
    acc[2] = fmaf(w1, bflo(v1.y), acc[2]); acc[3] = fmaf(w1, bfhi(v1.y), acc[3]);
    acc[4] = fmaf(w1, bflo(v1.z), acc[4]); acc[5] = fmaf(w1, bfhi(v1.z), acc[5]);
    acc[6] = fmaf(w1, bflo(v1.w), acc[6]); acc[7] = fmaf(w1, bfhi(v1.w), acc[7]);
  }
  if (j < deg) {
    int s = col[rs + j];
    float l = ns[s] + ndv;
    l = l >= 0.f ? l : NEG * l;
    float w = __expf(l);
    den += w;
    uint4 v = *(const uint4*)(xpc + (size_t)s * HC);
    acc[0] = fmaf(w, bflo(v.x), acc[0]); acc[1] = fmaf(w, bfhi(v.x), acc[1]);
    acc[2] = fmaf(w, bflo(v.y), acc[2]); acc[3] = fmaf(w, bfhi(v.y), acc[3]);
    acc[4] = fmaf(w, bflo(v.z), acc[4]); acc[5] = fmaf(w, bfhi(v.z), acc[5]);
    acc[6] = fmaf(w, bflo(v.w), acc[6]); acc[7] = fmaf(w, bfhi(v.w), acc[7]);
  }
#pragma unroll
  for (int off = 32; off >= LPE; off >>= 1) {
    den += __shfl_xor(den, off);
#pragma unroll
    for (int c = 0; c < CPL; ++c) acc[c] += __shfl_xor(acc[c], off);
  }
  if (eg != 0) return;
  float inv = 1.f / den;
  float o[CPL];
#pragma unroll
  for (int c = 0; c < CPL; ++c) o[c] = acc[c] * inv + bias[ch0 + c];
  if (!*flag) {
    float* op = (float*)outp + (size_t)n * HC + ch0;
    *(float4*)op = make_float4(o[0], o[1], o[2], o[3]);
    *(float4*)(op + 4) = make_float4(o[4], o[5], o[6], o[7]);
  } else {
    unsigned short* op = (unsigned short*)outp + (size_t)n * HC + ch0;
    uint4 pk;
    pk.x = (unsigned)f2bfu(o[0]) | ((unsigned)f2bfu(o[1]) << 16);
    pk.y = (unsigned)f2bfu(o[2]) | ((unsigned)f2bfu(o[3]) << 16);
    pk.z = (unsigned)f2bfu(o[4]) | ((unsigned)f2bfu(o[5]) << 16);
    pk.w = (unsigned)f2bfu(o[6]) | ((unsigned)f2bfu(o[7]) << 16);
    *(uint4*)op = pk;
  }
}

extern "C" void kernel_launch(void* const* d_in, const int* in_sizes, int n_in,
                              void* d_out, int out_size, void* d_ws, size_t ws_size,
                              hipStream_t stream) {
  const void* x  = d_in[0];
  const int* ei  = (const int*)d_in[1];
  const void* W1 = d_in[2];
  const void* as1 = d_in[3];
  const void* ad1 = d_in[4];
  const void* b1 = d_in[5];
  const void* W2 = d_in[6];
  const void* as2 = d_in[7];
  const void* ad2 = d_in[8];
  const void* b2 = d_in[9];
  const int* srcs = ei;
  const int* dsts = ei + NE;

  char* w = (char*)d_ws;
  auto alloc = [&](size_t bytes) {
    char* p = w;
    w += (bytes + 255) & ~(size_t)255;
    return p;
  };
  int* flag   = (int*)alloc(4);
  unsigned short* hb  = (unsigned short*)alloc((size_t)NN * HC1 * 2);
  unsigned short* W1b = (unsigned short*)alloc((size_t)CIN * HC1 * 2);
  unsigned short* W2b = (unsigned short*)alloc((size_t)HC1 * C2 * 2);
  unsigned short* xp1 = (unsigned short*)alloc((size_t)NN * HC1 * 2);  // head-major planes; reused as xp2
  float* nAS1 = (float*)alloc((size_t)NN * H1 * 4);  // head-major
  float* nAD1 = (float*)alloc((size_t)NN * H1 * 4);
  float* nAS2 = (float*)alloc((size_t)NN * 4);
  float* nAD2 = (float*)alloc((size_t)NN * 4);
  float* pAS1 = (float*)alloc((size_t)H1 * C1 * 4);
  float* pAD1 = (float*)alloc((size_t)H1 * C1 * 4);
  float* b1f  = (float*)alloc((size_t)HC1 * 4);
  float* pAS2 = (float*)alloc((size_t)C2 * 4);
  float* pAD2 = (float*)alloc((size_t)C2 * 4);
  float* b2f  = (float*)alloc((size_t)C2 * 4);
  int* rowptr = (int*)alloc((size_t)(NN + 1) * 4);
  int* gcnt   = (int*)alloc((size_t)NB1 * SBLK * 4);
  int* bucketReal = (int*)alloc((size_t)NB1 * 4);
  int* sBase  = (int*)alloc((size_t)NB1 * 4);
  int* colx   = (int*)alloc((size_t)ET * 4);
  unsigned* staging = (unsigned*)alloc((size_t)NE * 4);
  unsigned short* xp2 = xp1;

  k_detect<<<1, 256, 0, stream>>>((const unsigned short*)x, flag);
  k_params<<<(CIN * HC1 + HC1 * C2 + HC1 + C2 + 255) / 256, 256, 0, stream>>>(
      W1, W2, as1, ad1, b1, as2, ad2, b2,
      W1b, W2b, pAS1, pAD1, b1f, pAS2, pAD2, b2f, flag);

  // ---- CSR build (dense counting sort) ----
  k_histo<<<SBLK, 256, 0, stream>>>(dsts, gcnt);
  k_histscan<<<NB1, SBLK, 0, stream>>>(gcnt, bucketReal);
  k_base<<<1, 256, 0, stream>>>(bucketReal, sBase, rowptr);
  k_scatter<<<SBLK, 256, 0, stream>>>(srcs, dsts, gcnt, sBase, staging);
  k_bucket<<<NB1, 256, 0, stream>>>(staging, sBase, bucketReal, rowptr, colx);

  int gb = (NN + 127) / 128;  // 782 blocks (4 waves x 32 rows)
  // ---- layer 1 ----
  k_gemm_mfma<8, H1, true, true><<<gb, 256, 0, stream>>>(
      x, W1b, xp1, pAS1, pAD1, nAS1, nAD1, NN, flag);
  k_agg1h<<<12500 * 8, 256, 0, stream>>>(rowptr, colx, nAS1, nAD1, xp1, b1f, hb);

  // ---- layer 2 ----
  k_gemm_mfma<4, 1, false, false><<<gb, 256, 0, stream>>>(
      hb, W2b, xp2, pAS2, pAD2, nAS2, nAD2, NN, flag);
  k_agg2<<<(NN + 3) / 4, 256, 0, stream>>>(rowptr, colx, nAS2, nAD2, xp2, b2f, d_out, flag);
}

// Round 11
// 252.244 us; speedup vs baseline: 1.2442x; 1.2442x over previous
//
#include <hip/hip_runtime.h>
#include <hip/hip_bf16.h>
#include <math.h>

#define NN 100000
#define NE 1600000
#define ET (NE + NN)
#define CIN 128
#define H1 4
#define C1 32
#define HC1 128
#define C2 64
#define NEG 0.2f
#define NB1 196          // ceil(NN/512) coarse buckets (512 nodes each)
#define SBLK 256         // scatter blocks
#define ECHUNK ((NE + SBLK - 1) / SBLK)  // 6250 edges per scatter block
#define BCAP 12288       // bucket LDS capacity (entries); expected max ~9500

typedef __attribute__((ext_vector_type(8))) short short8v;
typedef __attribute__((ext_vector_type(4))) float f32x4;
typedef __attribute__((ext_vector_type(4))) unsigned int u32x4;

__device__ __forceinline__ float bfu2f(unsigned short u) {
  union { unsigned u; float f; } c; c.u = ((unsigned)u) << 16; return c.f;
}
__device__ __forceinline__ float bflo(unsigned v) {
  union { unsigned u; float f; } c; c.u = v << 16; return c.f;
}
__device__ __forceinline__ float bfhi(unsigned v) {
  union { unsigned u; float f; } c; c.u = v & 0xffff0000u; return c.f;
}
__device__ __forceinline__ unsigned short f2bfu(float f) {
  union { __hip_bfloat16 b; unsigned short u; } c; c.b = __float2bfloat16(f); return c.u;
}

// ---- dtype probe: are the float inputs bf16 or f32? ----
__global__ void k_detect(const unsigned short* __restrict__ x, int* __restrict__ flag) {
  __shared__ int cnt;
  if (threadIdx.x == 0) cnt = 0;
  __syncthreads();
  int bad = 0;
  for (int i = threadIdx.x; i < 2048; i += 256) {
    unsigned short u = x[i];
    int ex = (u >> 7) & 0xFF;
    bool ok = ((u & 0x7FFF) == 0) || (ex >= 90 && ex <= 140);
    if (!ok) bad++;
  }
  atomicAdd(&cnt, bad);
  __syncthreads();
  if (threadIdx.x == 0) *flag = (cnt * 10 < 2048) ? 1 : 0;  // 1 = bf16
}

// merged param conversion: W1->bf16, W2->bf16, att/bias->f32
__global__ void k_params(const void* __restrict__ W1, const void* __restrict__ W2,
                         const void* as1, const void* ad1, const void* b1,
                         const void* as2, const void* ad2, const void* b2,
                         unsigned short* __restrict__ W1b, unsigned short* __restrict__ W2b,
                         float* pAS1, float* pAD1, float* b1f,
                         float* pAS2, float* pAD2, float* b2f,
                         const int* __restrict__ flag) {
  int g = blockIdx.x * 256 + threadIdx.x;
  int isbf = *flag;
  auto cv = [&](const void* p, int idx) -> float {
    return isbf ? bfu2f(((const unsigned short*)p)[idx]) : ((const float*)p)[idx];
  };
  if (g < CIN * HC1) {
    W1b[g] = isbf ? ((const unsigned short*)W1)[g] : f2bfu(((const float*)W1)[g]);
  } else if (g < CIN * HC1 + HC1 * C2) {
    int i = g - CIN * HC1;
    W2b[i] = isbf ? ((const unsigned short*)W2)[i] : f2bfu(((const float*)W2)[i]);
  } else {
    int i = g - (CIN * HC1 + HC1 * C2);
    if (i < HC1) { pAS1[i] = cv(as1, i); pAD1[i] = cv(ad1, i); b1f[i] = cv(b1, i); }
    else if (i < HC1 + C2) {
      int j = i - HC1;
      pAS2[j] = cv(as2, j); pAD2[j] = cv(ad2, j); b2f[j] = cv(b2, j);
    }
  }
}

// ================= CSR build: dense counting sort, no global atomics ========
__global__ __launch_bounds__(256) void k_histo(
    const int* __restrict__ dst, int* __restrict__ gcnt) {
  __shared__ int hist[NB1];
  for (int b = threadIdx.x; b < NB1; b += 256) hist[b] = 0;
  __syncthreads();
  int e0 = blockIdx.x * ECHUNK;
  int e1 = min(e0 + ECHUNK, NE);
  for (int e = e0 + threadIdx.x; e < e1; e += 256)
    atomicAdd(&hist[__builtin_nontemporal_load(dst + e) >> 9], 1);
  __syncthreads();
  for (int b = threadIdx.x; b < NB1; b += 256)
    gcnt[b * SBLK + blockIdx.x] = hist[b];
}

__global__ void k_histscan(int* __restrict__ gcnt, int* __restrict__ bucketReal) {
  __shared__ int sm[SBLK];
  int b = blockIdx.x;
  int t = threadIdx.x;
  int v = gcnt[b * SBLK + t];
  sm[t] = v;
  __syncthreads();
  for (int off = 1; off < SBLK; off <<= 1) {
    int tmp = (t >= off) ? sm[t - off] : 0;
    __syncthreads();
    sm[t] += tmp;
    __syncthreads();
  }
  gcnt[b * SBLK + t] = sm[t] - v;  // exclusive
  if (t == SBLK - 1) bucketReal[b] = sm[SBLK - 1];
}

__global__ void k_base(const int* __restrict__ bucketReal, int* __restrict__ sBase,
                       int* __restrict__ rowptr) {
  __shared__ int sm[256];
  int t = threadIdx.x;
  int v = (t < NB1) ? bucketReal[t] : 0;
  sm[t] = v;
  __syncthreads();
  for (int off = 1; off < 256; off <<= 1) {
    int tmp = (t >= off) ? sm[t - off] : 0;
    __syncthreads();
    sm[t] += tmp;
    __syncthreads();
  }
  if (t < NB1) sBase[t] = sm[t] - v;  // exclusive (real edges only)
  if (t == 0) rowptr[NN] = ET;
}

// scatter packed (src | dstLow<<17) into bucket-major staging; dense-run writes
__global__ __launch_bounds__(256) void k_scatter(
    const int* __restrict__ src, const int* __restrict__ dst,
    const int* __restrict__ gcnt, const int* __restrict__ sBase,
    unsigned* __restrict__ staging) {
  __shared__ int lcur[NB1];
  for (int b = threadIdx.x; b < NB1; b += 256)
    lcur[b] = sBase[b] + gcnt[b * SBLK + blockIdx.x];
  __syncthreads();
  int e0 = blockIdx.x * ECHUNK;
  int e1 = min(e0 + ECHUNK, NE);
  for (int e = e0 + threadIdx.x; e < e1; e += 256) {
    int s = __builtin_nontemporal_load(src + e);
    int d = __builtin_nontemporal_load(dst + e);
    int pos = atomicAdd(&lcur[d >> 9], 1);
    staging[pos] = (unsigned)s | ((unsigned)(d & 511) << 17);
  }
}

// per-bucket: node histogram -> scan -> rowptr + sorted col (LDS staged)
__global__ __launch_bounds__(256) void k_bucket(
    const unsigned* __restrict__ staging, const int* __restrict__ sBase,
    const int* __restrict__ bucketReal, int* __restrict__ rowptr,
    int* __restrict__ col) {
  __shared__ int lhist[512];
  __shared__ int lcol[BCAP];
  __shared__ int ps[256];
  int b = blockIdx.x;
  int t = threadIdx.x;
  int n0 = b << 9;
  int nc = min(512, NN - n0);
  int sb = sBase[b];
  int realE = bucketReal[b];
  int regionStart = sb + n0;  // prior buckets each contribute 512 self-loops
  int total = realE + nc;
  lhist[t] = (t < nc) ? 1 : 0;            // self-loop
  lhist[t + 256] = (t + 256 < nc) ? 1 : 0;
  __syncthreads();
  for (int i = t; i < realE; i += 256)
    atomicAdd(&lhist[staging[sb + i] >> 17], 1);
  __syncthreads();
  // exclusive scan of 512 counters
  int v0 = lhist[t * 2], v1 = lhist[t * 2 + 1];
  int run = v0 + v1;
  ps[t] = run;
  __syncthreads();
  for (int off = 1; off < 256; off <<= 1) {
    int tmp = (t >= off) ? ps[t - off] : 0;
    __syncthreads();
    ps[t] += tmp;
    __syncthreads();
  }
  int base = ps[t] - run;
  lhist[t * 2] = base;
  lhist[t * 2 + 1] = base + v0;
  __syncthreads();
  // rowptr (before cursors mutate)
  for (int i = t; i < nc; i += 256)
    rowptr[n0 + i] = regionStart + lhist[i];
  __syncthreads();
  // self-loops first, then real edges
  for (int i = t; i < nc; i += 256) {
    int r = atomicAdd(&lhist[i], 1);
    if (r < BCAP) lcol[r] = n0 + i;
    else col[regionStart + r] = n0 + i;
  }
  for (int i = t; i < realE; i += 256) {
    unsigned p = staging[sb + i];
    int r = atomicAdd(&lhist[p >> 17], 1);
    int sv = (int)(p & 0x1FFFFu);
    if (r < BCAP) lcol[r] = sv;
    else col[regionStart + r] = sv;
  }
  __syncthreads();
  int lim = min(total, BCAP);
  for (int i = t; i < lim; i += 256)
    __builtin_nontemporal_store(lcol[i], col + regionStart + i);
}

// ================= bf16 MFMA GEMM + fused attention dots =================
template<int NT, int H, bool MAYBE_F32>  // NC = NT*16
__global__ __launch_bounds__(256) void k_gemm_mfma(
    const void* __restrict__ Araw, const unsigned short* __restrict__ W,
    unsigned short* __restrict__ Cb, const float* __restrict__ attS,
    const float* __restrict__ attD, float* __restrict__ ns,
    float* __restrict__ nd, int M, const int* __restrict__ flag) {
  constexpr int NC = NT * 16;
  __shared__ __align__(16) unsigned short lds[NC * 128];
  int t = threadIdx.x;
#pragma unroll
  for (int r = 0; r < (128 * NC) / (256 * 8); ++r) {
    int f = (t + r * 256) * 8;
    int k = f / NC;
    int n0 = f - k * NC;  // multiple of 8
    short8v v = *(const short8v*)(W + k * NC + n0);
#pragma unroll
    for (int j = 0; j < 8; ++j) {
      int n = n0 + j;
      lds[n * 128 + (((k >> 3) ^ (n & 7)) << 3) + (k & 7)] = ((const unsigned short*)&v)[j];
    }
  }
  __syncthreads();
  int wave = t >> 6, lane = t & 63;
  int m0 = (blockIdx.x * 4 + wave) * 32;
  if (m0 >= M) return;
  int isbf = MAYBE_F32 ? *flag : 1;
  f32x4 acc[2][NT];
#pragma unroll
  for (int mt = 0; mt < 2; ++mt)
#pragma unroll
    for (int nt = 0; nt < NT; ++nt) acc[mt][nt] = (f32x4)(0.f);
  int r0 = m0 + (lane & 15);
  int koff = (lane >> 4) << 3;
#pragma unroll
  for (int ks = 0; ks < 4; ++ks) {
    short8v af0, af1;
    if (isbf) {
      const unsigned short* A = (const unsigned short*)Araw;
      af0 = *(const short8v*)(A + (size_t)r0 * 128 + koff + ks * 32);
      af1 = *(const short8v*)(A + (size_t)(r0 + 16) * 128 + koff + ks * 32);
    } else {
      const float* A = (const float*)Araw;
      const float* p0 = A + (size_t)r0 * 128 + koff + ks * 32;
      const float* p1 = A + (size_t)(r0 + 16) * 128 + koff + ks * 32;
      float4 u0 = *(const float4*)p0, u1 = *(const float4*)(p0 + 4);
      float4 v0 = *(const float4*)p1, v1 = *(const float4*)(p1 + 4);
      unsigned short* a0 = (unsigned short*)&af0;
      unsigned short* a1 = (unsigned short*)&af1;
      a0[0] = f2bfu(u0.x); a0[1] = f2bfu(u0.y); a0[2] = f2bfu(u0.z); a0[3] = f2bfu(u0.w);
      a0[4] = f2bfu(u1.x); a0[5] = f2bfu(u1.y); a0[6] = f2bfu(u1.z); a0[7] = f2bfu(u1.w);
      a1[0] = f2bfu(v0.x); a1[1] = f2bfu(v0.y); a1[2] = f2bfu(v0.z); a1[3] = f2bfu(v0.w);
      a1[4] = f2bfu(v1.x); a1[5] = f2bfu(v1.y); a1[6] = f2bfu(v1.z); a1[7] = f2bfu(v1.w);
    }
#pragma unroll
    for (int nt = 0; nt < NT; ++nt) {
      int n = nt * 16 + (lane & 15);
      int chunk = ks * 4 + (lane >> 4);
      short8v bf = *(const short8v*)&lds[n * 128 + ((chunk ^ (n & 7)) << 3)];
      acc[0][nt] = __builtin_amdgcn_mfma_f32_16x16x32_bf16(af0, bf, acc[0][nt], 0, 0, 0);
      acc[1][nt] = __builtin_amdgcn_mfma_f32_16x16x32_bf16(af1, bf, acc[1][nt], 0, 0, 0);
    }
  }
  constexpr int NPH = NT / H;
#pragma unroll
  for (int mt = 0; mt < 2; ++mt) {
    int mb = m0 + mt * 16;
#pragma unroll
    for (int nt = 0; nt < NT; ++nt)
#pragma unroll
      for (int r = 0; r < 4; ++r) {
        int row = ((lane >> 4) << 2) + r;
        Cb[(size_t)(mb + row) * NC + nt * 16 + (lane & 15)] = f2bfu(acc[mt][nt][r]);
      }
#pragma unroll
    for (int r = 0; r < 4; ++r) {
      int row = mb + ((lane >> 4) << 2) + r;
#pragma unroll
      for (int h = 0; h < H; ++h) {
        float ps = 0.f, pd = 0.f;
#pragma unroll
        for (int q = 0; q < NPH; ++q) {
          int nt = h * NPH + q;
          int ch = nt * 16 + (lane & 15);
          ps = fmaf(acc[mt][nt][r], attS[ch], ps);
          pd = fmaf(acc[mt][nt][r], attD[ch], pd);
        }
#pragma unroll
        for (int off = 8; off; off >>= 1) {
          ps += __shfl_xor(ps, off);
          pd += __shfl_xor(pd, off);
        }
        if ((lane & 15) == 0) { ns[row * H + h] = ps; nd[row * H + h] = pd; }
      }
    }
  }
}

// ================= fused gather aggregation, edge-transposed ================
template<int CPL>
__device__ __forceinline__ void accum(float w, const unsigned short* p, float* acc) {
#pragma unroll
  for (int q = 0; q < CPL / 8; ++q) {
    uint4 v = *(const uint4*)(p + q * 8);
    acc[q * 8 + 0] = fmaf(w, bflo(v.x), acc[q * 8 + 0]);
    acc[q * 8 + 1] = fmaf(w, bfhi(v.x), acc[q * 8 + 1]);
    acc[q * 8 + 2] = fmaf(w, bflo(v.y), acc[q * 8 + 2]);
    acc[q * 8 + 3] = fmaf(w, bfhi(v.y), acc[q * 8 + 3]);
    acc[q * 8 + 4] = fmaf(w, bflo(v.z), acc[q * 8 + 4]);
    acc[q * 8 + 5] = fmaf(w, bfhi(v.z), acc[q * 8 + 5]);
    acc[q * 8 + 6] = fmaf(w, bflo(v.w), acc[q * 8 + 6]);
    acc[q * 8 + 7] = fmaf(w, bfhi(v.w), acc[q * 8 + 7]);
  }
}

template<int H, int C, int LPE, bool DOELU, bool FINAL>
__global__ __launch_bounds__(256) void k_agg(
    const int* __restrict__ rowptr, const int* __restrict__ col,
    const float* __restrict__ ns, const float* __restrict__ nd,
    const unsigned short* __restrict__ xp, const float* __restrict__ bias,
    void* __restrict__ outp, const int* __restrict__ flag) {
  constexpr int HC = H * C;
  constexpr int CPL = HC / LPE;
  constexpr int EPW = 64 / LPE;
  int wave = threadIdx.x >> 6;
  int lane = threadIdx.x & 63;
  int n = blockIdx.x * 4 + wave;
  if (n >= NN) return;
  int rs = rowptr[n];
  int deg = rowptr[n + 1] - rs;
  int le = lane & (LPE - 1);   // lane within edge
  int eg = lane / LPE;         // edge group
  int ch0 = le * CPL;
  int h = (H == 1) ? 0 : (ch0 / C);
  float ndv = nd[n * H + h];
  const unsigned short* xpc = xp + ch0;
  float den = 0.f;
  float acc[CPL];
#pragma unroll
  for (int c = 0; c < CPL; ++c) acc[c] = 0.f;
  int j = eg;
  for (; j + EPW < deg; j += 2 * EPW) {
    int s0 = __builtin_nontemporal_load(col + rs + j);
    int s1 = __builtin_nontemporal_load(col + rs + j + EPW);
    float l0 = ns[s0 * H + h] + ndv, l1 = ns[s1 * H + h] + ndv;
    l0 = l0 >= 0.f ? l0 : NEG * l0;
    l1 = l1 >= 0.f ? l1 : NEG * l1;
    float w0 = __expf(l0), w1 = __expf(l1);
    den += w0 + w1;
    const unsigned short* p0 = xpc + (size_t)s0 * HC;
    const unsigned short* p1 = xpc + (size_t)s1 * HC;
    accum<CPL>(w0, p0, acc);
    accum<CPL>(w1, p1, acc);
  }
  if (j < deg) {
    int s = __builtin_nontemporal_load(col + rs + j);
    float l = ns[s * H + h] + ndv;
    l = l >= 0.f ? l : NEG * l;
    float w = __expf(l);
    den += w;
    accum<CPL>(w, xpc + (size_t)s * HC, acc);
  }
  // butterfly reduce across edge groups
#pragma unroll
  for (int off = 32; off >= LPE; off >>= 1) {
    den += __shfl_xor(den, off);
#pragma unroll
    for (int c = 0; c < CPL; ++c) acc[c] += __shfl_xor(acc[c], off);
  }
  if (eg != 0) return;
  float inv = 1.f / den;
  float o[CPL];
#pragma unroll
  for (int c = 0; c < CPL; ++c) {
    o[c] = acc[c] * inv + bias[ch0 + c];
    if (DOELU) o[c] = o[c] > 0.f ? o[c] : __expf(o[c]) - 1.f;
  }
  if (FINAL && !*flag) {
    float* op = (float*)outp + (size_t)n * HC + ch0;
#pragma unroll
    for (int q = 0; q < CPL / 4; ++q) {
      f32x4 fv;
      fv[0] = o[q * 4]; fv[1] = o[q * 4 + 1]; fv[2] = o[q * 4 + 2]; fv[3] = o[q * 4 + 3];
      __builtin_nontemporal_store(fv, (f32x4*)(op + q * 4));
    }
  } else {
    unsigned short* op = (unsigned short*)outp + (size_t)n * HC + ch0;
#pragma unroll
    for (int q = 0; q < CPL / 8; ++q) {
      u32x4 pk;
      pk[0] = (unsigned)f2bfu(o[q * 8 + 0]) | ((unsigned)f2bfu(o[q * 8 + 1]) << 16);
      pk[1] = (unsigned)f2bfu(o[q * 8 + 2]) | ((unsigned)f2bfu(o[q * 8 + 3]) << 16);
      pk[2] = (unsigned)f2bfu(o[q * 8 + 4]) | ((unsigned)f2bfu(o[q * 8 + 5]) << 16);
      pk[3] = (unsigned)f2bfu(o[q * 8 + 6]) | ((unsigned)f2bfu(o[q * 8 + 7]) << 16);
      __builtin_nontemporal_store(pk, (u32x4*)(op + q * 8));
    }
  }
}

extern "C" void kernel_launch(void* const* d_in, const int* in_sizes, int n_in,
                              void* d_out, int out_size, void* d_ws, size_t ws_size,
                              hipStream_t stream) {
  const void* x  = d_in[0];
  const int* ei  = (const int*)d_in[1];
  const void* W1 = d_in[2];
  const void* as1 = d_in[3];
  const void* ad1 = d_in[4];
  const void* b1 = d_in[5];
  const void* W2 = d_in[6];
  const void* as2 = d_in[7];
  const void* ad2 = d_in[8];
  const void* b2 = d_in[9];
  const int* srcs = ei;
  const int* dsts = ei + NE;

  char* w = (char*)d_ws;
  auto alloc = [&](size_t bytes) {
    char* p = w;
    w += (bytes + 255) & ~(size_t)255;
    return p;
  };
  int* flag   = (int*)alloc(4);
  unsigned short* hb  = (unsigned short*)alloc((size_t)NN * HC1 * 2);
  unsigned short* W1b = (unsigned short*)alloc((size_t)CIN * HC1 * 2);
  unsigned short* W2b = (unsigned short*)alloc((size_t)HC1 * C2 * 2);
  unsigned short* xp1 = (unsigned short*)alloc((size_t)NN * HC1 * 2);  // reused as xp2
  float* nAS1 = (float*)alloc((size_t)NN * H1 * 4);
  float* nAD1 = (float*)alloc((size_t)NN * H1 * 4);
  float* nAS2 = (float*)alloc((size_t)NN * 4);
  float* nAD2 = (float*)alloc((size_t)NN * 4);
  float* pAS1 = (float*)alloc((size_t)H1 * C1 * 4);
  float* pAD1 = (float*)alloc((size_t)H1 * C1 * 4);
  float* b1f  = (float*)alloc((size_t)HC1 * 4);
  float* pAS2 = (float*)alloc((size_t)C2 * 4);
  float* pAD2 = (float*)alloc((size_t)C2 * 4);
  float* b2f  = (float*)alloc((size_t)C2 * 4);
  int* rowptr = (int*)alloc((size_t)(NN + 1) * 4);
  int* gcnt   = (int*)alloc((size_t)NB1 * SBLK * 4);
  int* bucketReal = (int*)alloc((size_t)NB1 * 4);
  int* sBase  = (int*)alloc((size_t)NB1 * 4);
  int* colx   = (int*)alloc((size_t)ET * 4);
  unsigned* staging = (unsigned*)alloc((size_t)NE * 4);
  unsigned short* xp2 = xp1;  // xp1 dead after layer-1 aggregation

  k_detect<<<1, 256, 0, stream>>>((const unsigned short*)x, flag);
  k_params<<<(CIN * HC1 + HC1 * C2 + HC1 + C2 + 255) / 256, 256, 0, stream>>>(
      W1, W2, as1, ad1, b1, as2, ad2, b2,
      W1b, W2b, pAS1, pAD1, b1f, pAS2, pAD2, b2f, flag);

  // ---- CSR build (dense counting sort) ----
  k_histo<<<SBLK, 256, 0, stream>>>(dsts, gcnt);
  k_histscan<<<NB1, SBLK, 0, stream>>>(gcnt, bucketReal);
  k_base<<<1, 256, 0, stream>>>(bucketReal, sBase, rowptr);
  k_scatter<<<SBLK, 256, 0, stream>>>(srcs, dsts, gcnt, sBase, staging);
  k_bucket<<<NB1, 256, 0, stream>>>(staging, sBase, bucketReal, rowptr, colx);

  int gb = (NN + 127) / 128;  // 782 blocks (4 waves x 32 rows)
  // ---- layer 1 ----
  k_gemm_mfma<8, H1, true><<<gb, 256, 0, stream>>>(
      x, W1b, xp1, pAS1, pAD1, nAS1, nAD1, NN, flag);
  k_agg<H1, C1, 8, true, false><<<(NN + 3) / 4, 256, 0, stream>>>(
      rowptr, colx, nAS1, nAD1, xp1, b1f, hb, flag);

  // ---- layer 2 ----
  k_gemm_mfma<4, 1, false><<<gb, 256, 0, stream>>>(
      hb, W2b, xp2, pAS2, pAD2, nAS2, nAD2, NN, flag);
  k_agg<1, C2, 8, false, true><<<(NN + 3) / 4, 256, 0, stream>>>(
      rowptr, colx, nAS2, nAD2, xp2, b2f, d_out, flag);
}

// Round 12
// 232.697 us; speedup vs baseline: 1.3487x; 1.0840x over previous
//
#include <hip/hip_runtime.h>
#include <hip/hip_bf16.h>
#include <math.h>

#define NN 100000
#define NE 1600000
#define ET (NE + NN)
#define CIN 128
#define H1 4
#define C1 32
#define HC1 128
#define C2 64
#define NEG 0.2f
#define NB1 196          // ceil(NN/512) coarse buckets (512 nodes each)
#define SBLK 256         // scatter blocks
#define ECHUNK ((NE + SBLK - 1) / SBLK)  // 6250 edges per scatter block
#define BCAP 12288       // bucket LDS capacity (entries); expected max ~9500
#define WN 13            // src windows of 8192 nodes
#define CURN (512 * WN)  // 6656 per-bucket (node,window) counters

typedef __attribute__((ext_vector_type(8))) short short8v;
typedef __attribute__((ext_vector_type(4))) float f32x4;

__device__ __forceinline__ float bfu2f(unsigned short u) {
  union { unsigned u; float f; } c; c.u = ((unsigned)u) << 16; return c.f;
}
__device__ __forceinline__ float bflo(unsigned v) {
  union { unsigned u; float f; } c; c.u = v << 16; return c.f;
}
__device__ __forceinline__ float bfhi(unsigned v) {
  union { unsigned u; float f; } c; c.u = v & 0xffff0000u; return c.f;
}
__device__ __forceinline__ unsigned short f2bfu(float f) {
  union { __hip_bfloat16 b; unsigned short u; } c; c.b = __float2bfloat16(f); return c.u;
}

// ---- dtype probe: are the float inputs bf16 or f32? ----
__global__ void k_detect(const unsigned short* __restrict__ x, int* __restrict__ flag) {
  __shared__ int cnt;
  if (threadIdx.x == 0) cnt = 0;
  __syncthreads();
  int bad = 0;
  for (int i = threadIdx.x; i < 2048; i += 256) {
    unsigned short u = x[i];
    int ex = (u >> 7) & 0xFF;
    bool ok = ((u & 0x7FFF) == 0) || (ex >= 90 && ex <= 140);
    if (!ok) bad++;
  }
  atomicAdd(&cnt, bad);
  __syncthreads();
  if (threadIdx.x == 0) *flag = (cnt * 10 < 2048) ? 1 : 0;  // 1 = bf16
}

// merged param conversion: W1->bf16, W2->bf16, att/bias->f32
__global__ void k_params(const void* __restrict__ W1, const void* __restrict__ W2,
                         const void* as1, const void* ad1, const void* b1,
                         const void* as2, const void* ad2, const void* b2,
                         unsigned short* __restrict__ W1b, unsigned short* __restrict__ W2b,
                         float* pAS1, float* pAD1, float* b1f,
                         float* pAS2, float* pAD2, float* b2f,
                         const int* __restrict__ flag) {
  int g = blockIdx.x * 256 + threadIdx.x;
  int isbf = *flag;
  auto cv = [&](const void* p, int idx) -> float {
    return isbf ? bfu2f(((const unsigned short*)p)[idx]) : ((const float*)p)[idx];
  };
  if (g < CIN * HC1) {
    W1b[g] = isbf ? ((const unsigned short*)W1)[g] : f2bfu(((const float*)W1)[g]);
  } else if (g < CIN * HC1 + HC1 * C2) {
    int i = g - CIN * HC1;
    W2b[i] = isbf ? ((const unsigned short*)W2)[i] : f2bfu(((const float*)W2)[i]);
  } else {
    int i = g - (CIN * HC1 + HC1 * C2);
    if (i < HC1) { pAS1[i] = cv(as1, i); pAD1[i] = cv(ad1, i); b1f[i] = cv(b1, i); }
    else if (i < HC1 + C2) {
      int j = i - HC1;
      pAS2[j] = cv(as2, j); pAD2[j] = cv(ad2, j); b2f[j] = cv(b2, j);
    }
  }
}

// ================= CSR build: dense counting sort, no global atomics ========
// per-(bucket, block) histogram of real edges
__global__ __launch_bounds__(256) void k_histo(
    const int* __restrict__ dst, int* __restrict__ gcnt) {
  __shared__ int hist[NB1];
  for (int b = threadIdx.x; b < NB1; b += 256) hist[b] = 0;
  __syncthreads();
  int e0 = blockIdx.x * ECHUNK;
  int e1 = min(e0 + ECHUNK, NE);
  for (int e = e0 + threadIdx.x; e < e1; e += 256)
    atomicAdd(&hist[dst[e] >> 9], 1);
  __syncthreads();
  for (int b = threadIdx.x; b < NB1; b += 256)
    gcnt[b * SBLK + blockIdx.x] = hist[b];
}

// per-bucket scan of gcnt[b][0..255] -> bucket-relative exclusive offsets
__global__ void k_histscan(int* __restrict__ gcnt, int* __restrict__ bucketReal) {
  __shared__ int sm[SBLK];
  int b = blockIdx.x;
  int t = threadIdx.x;
  int v = gcnt[b * SBLK + t];
  sm[t] = v;
  __syncthreads();
  for (int off = 1; off < SBLK; off <<= 1) {
    int tmp = (t >= off) ? sm[t - off] : 0;
    __syncthreads();
    sm[t] += tmp;
    __syncthreads();
  }
  gcnt[b * SBLK + t] = sm[t] - v;  // exclusive
  if (t == SBLK - 1) bucketReal[b] = sm[SBLK - 1];
}

// 1-block scan of bucket totals -> staging bases; sentinel rowptr2
__global__ void k_base(const int* __restrict__ bucketReal, int* __restrict__ sBase,
                       int* __restrict__ rowptr2) {
  __shared__ int sm[256];
  int t = threadIdx.x;
  int v = (t < NB1) ? bucketReal[t] : 0;
  sm[t] = v;
  __syncthreads();
  for (int off = 1; off < 256; off <<= 1) {
    int tmp = (t >= off) ? sm[t - off] : 0;
    __syncthreads();
    sm[t] += tmp;
    __syncthreads();
  }
  if (t < NB1) sBase[t] = sm[t] - v;  // exclusive (real edges only)
  if (t == 0) rowptr2[(size_t)NN * WN] = ET;
}

// scatter packed (src | dstLow<<17) into bucket-major staging; dense-run writes
__global__ __launch_bounds__(256) void k_scatter(
    const int* __restrict__ src, const int* __restrict__ dst,
    const int* __restrict__ gcnt, const int* __restrict__ sBase,
    unsigned* __restrict__ staging) {
  __shared__ int lcur[NB1];
  for (int b = threadIdx.x; b < NB1; b += 256)
    lcur[b] = sBase[b] + gcnt[b * SBLK + blockIdx.x];
  __syncthreads();
  int e0 = blockIdx.x * ECHUNK;
  int e1 = min(e0 + ECHUNK, NE);
  for (int e = e0 + threadIdx.x; e < e1; e += 256) {
    int s = src[e], d = dst[e];
    int pos = atomicAdd(&lcur[d >> 9], 1);
    staging[pos] = (unsigned)s | ((unsigned)(d & 511) << 17);
  }
}

// per-bucket: local (node,window) histogram -> scan -> rowptr2 + sorted col.
// Edges within each node's list are sorted by src window (8192 nodes/window).
__global__ __launch_bounds__(256) void k_bucket2(
    const unsigned* __restrict__ staging, const int* __restrict__ sBase,
    const int* __restrict__ bucketReal, int* __restrict__ rowptr2,
    int* __restrict__ col) {
  __shared__ int lhist[CURN];
  __shared__ int lcol[BCAP];
  __shared__ int ps[256];
  int b = blockIdx.x;
  int t = threadIdx.x;
  int n0 = b << 9;
  int nc = min(512, NN - n0);
  int sb = sBase[b];
  int realE = bucketReal[b];
  int regionStart = sb + n0;  // cBase: all prior buckets have 512 nodes
  int total = realE + nc;
#pragma unroll
  for (int q = 0; q < CURN / 256; ++q) lhist[t + q * 256] = 0;
  __syncthreads();
  // pass 1: histogram (real edges + self-loops)
  for (int i = t; i < realE; i += 256) {
    unsigned p = staging[sb + i];
    int d = (int)(p >> 17);
    int w = (int)((p & 0x1FFFFu) >> 13);
    atomicAdd(&lhist[d * WN + w], 1);
  }
  for (int i = t; i < nc; i += 256)
    atomicAdd(&lhist[i * WN + ((n0 + i) >> 13)], 1);
  __syncthreads();
  // exclusive scan of lhist[0..CURN)
  constexpr int CHUNK = CURN / 256;  // 26
  int vals[CHUNK];
  int run = 0;
#pragma unroll
  for (int i = 0; i < CHUNK; ++i) { vals[i] = lhist[t * CHUNK + i]; run += vals[i]; }
  ps[t] = run;
  __syncthreads();
  for (int off = 1; off < 256; off <<= 1) {
    int tmp = (t >= off) ? ps[t - off] : 0;
    __syncthreads();
    ps[t] += tmp;
    __syncthreads();
  }
  int base = ps[t] - run;
#pragma unroll
  for (int i = 0; i < CHUNK; ++i) { lhist[t * CHUNK + i] = base; base += vals[i]; }
  __syncthreads();
  // rowptr2 write (reads lhist before cursors mutate)
  for (int i = t; i < nc * WN; i += 256)
    rowptr2[(size_t)n0 * WN + i] = regionStart + lhist[i];
  __syncthreads();
  // place self-loops, then real edges, via LDS cursors
  for (int i = t; i < nc; i += 256) {
    int r = atomicAdd(&lhist[i * WN + ((n0 + i) >> 13)], 1);
    if (r < BCAP) lcol[r] = n0 + i;
    else col[regionStart + r] = n0 + i;
  }
  for (int i = t; i < realE; i += 256) {
    unsigned p = staging[sb + i];
    int d = (int)(p >> 17);
    int s = (int)(p & 0x1FFFFu);
    int r = atomicAdd(&lhist[d * WN + (s >> 13)], 1);
    if (r < BCAP) lcol[r] = s;
    else col[regionStart + r] = s;
  }
  __syncthreads();
  int lim = min(total, BCAP);
  for (int i = t; i < lim; i += 256)
    col[regionStart + i] = lcol[i];
}

// ================= bf16 MFMA GEMM + fused attention dots =================
// 32 rows/wave (2 M-tiles share each B-fragment), A read directly from input
// (runtime bf16/f32 branch when MAYBE_F32).
template<int NT, int H, bool MAYBE_F32>  // NC = NT*16
__global__ __launch_bounds__(256) void k_gemm_mfma(
    const void* __restrict__ Araw, const unsigned short* __restrict__ W,
    unsigned short* __restrict__ Cb, const float* __restrict__ attS,
    const float* __restrict__ attD, float* __restrict__ ns,
    float* __restrict__ nd, int M, const int* __restrict__ flag) {
  constexpr int NC = NT * 16;
  __shared__ __align__(16) unsigned short lds[NC * 128];
  int t = threadIdx.x;
#pragma unroll
  for (int r = 0; r < (128 * NC) / (256 * 8); ++r) {
    int f = (t + r * 256) * 8;
    int k = f / NC;
    int n0 = f - k * NC;  // multiple of 8
    short8v v = *(const short8v*)(W + k * NC + n0);
#pragma unroll
    for (int j = 0; j < 8; ++j) {
      int n = n0 + j;
      lds[n * 128 + (((k >> 3) ^ (n & 7)) << 3) + (k & 7)] = ((const unsigned short*)&v)[j];
    }
  }
  __syncthreads();
  int wave = t >> 6, lane = t & 63;
  int m0 = (blockIdx.x * 4 + wave) * 32;
  if (m0 >= M) return;
  int isbf = MAYBE_F32 ? *flag : 1;
  f32x4 acc[2][NT];
#pragma unroll
  for (int mt = 0; mt < 2; ++mt)
#pragma unroll
    for (int nt = 0; nt < NT; ++nt) acc[mt][nt] = (f32x4)(0.f);
  int r0 = m0 + (lane & 15);
  int koff = (lane >> 4) << 3;
#pragma unroll
  for (int ks = 0; ks < 4; ++ks) {
    short8v af0, af1;
    if (isbf) {
      const unsigned short* A = (const unsigned short*)Araw;
      af0 = *(const short8v*)(A + (size_t)r0 * 128 + koff + ks * 32);
      af1 = *(const short8v*)(A + (size_t)(r0 + 16) * 128 + koff + ks * 32);
    } else {
      const float* A = (const float*)Araw;
      const float* p0 = A + (size_t)r0 * 128 + koff + ks * 32;
      const float* p1 = A + (size_t)(r0 + 16) * 128 + koff + ks * 32;
      float4 u0 = *(const float4*)p0, u1 = *(const float4*)(p0 + 4);
      float4 v0 = *(const float4*)p1, v1 = *(const float4*)(p1 + 4);
      unsigned short* a0 = (unsigned short*)&af0;
      unsigned short* a1 = (unsigned short*)&af1;
      a0[0] = f2bfu(u0.x); a0[1] = f2bfu(u0.y); a0[2] = f2bfu(u0.z); a0[3] = f2bfu(u0.w);
      a0[4] = f2bfu(u1.x); a0[5] = f2bfu(u1.y); a0[6] = f2bfu(u1.z); a0[7] = f2bfu(u1.w);
      a1[0] = f2bfu(v0.x); a1[1] = f2bfu(v0.y); a1[2] = f2bfu(v0.z); a1[3] = f2bfu(v0.w);
      a1[4] = f2bfu(v1.x); a1[5] = f2bfu(v1.y); a1[6] = f2bfu(v1.z); a1[7] = f2bfu(v1.w);
    }
#pragma unroll
    for (int nt = 0; nt < NT; ++nt) {
      int n = nt * 16 + (lane & 15);
      int chunk = ks * 4 + (lane >> 4);
      short8v bf = *(const short8v*)&lds[n * 128 + ((chunk ^ (n & 7)) << 3)];
      acc[0][nt] = __builtin_amdgcn_mfma_f32_16x16x32_bf16(af0, bf, acc[0][nt], 0, 0, 0);
      acc[1][nt] = __builtin_amdgcn_mfma_f32_16x16x32_bf16(af1, bf, acc[1][nt], 0, 0, 0);
    }
  }
  constexpr int NPH = NT / H;
#pragma unroll
  for (int mt = 0; mt < 2; ++mt) {
    int mb = m0 + mt * 16;
#pragma unroll
    for (int nt = 0; nt < NT; ++nt)
#pragma unroll
      for (int r = 0; r < 4; ++r) {
        int row = ((lane >> 4) << 2) + r;
        Cb[(size_t)(mb + row) * NC + nt * 16 + (lane & 15)] = f2bfu(acc[mt][nt][r]);
      }
#pragma unroll
    for (int r = 0; r < 4; ++r) {
      int row = mb + ((lane >> 4) << 2) + r;
#pragma unroll
      for (int h = 0; h < H; ++h) {
        float ps = 0.f, pd = 0.f;
#pragma unroll
        for (int q = 0; q < NPH; ++q) {
          int nt = h * NPH + q;
          int ch = nt * 16 + (lane & 15);
          ps = fmaf(acc[mt][nt][r], attS[ch], ps);
          pd = fmaf(acc[mt][nt][r], attD[ch], pd);
        }
#pragma unroll
        for (int off = 8; off; off >>= 1) {
          ps += __shfl_xor(ps, off);
          pd += __shfl_xor(pd, off);
        }
        if ((lane & 15) == 0) { ns[row * H + h] = ps; nd[row * H + h] = pd; }
      }
    }
  }
}

// ================= fused gather aggregation, edge-transposed ================
template<int CPL>
__device__ __forceinline__ void accum(float w, const unsigned short* p, float* acc) {
#pragma unroll
  for (int q = 0; q < CPL / 8; ++q) {
    uint4 v = *(const uint4*)(p + q * 8);
    acc[q * 8 + 0] = fmaf(w, bflo(v.x), acc[q * 8 + 0]);
    acc[q * 8 + 1] = fmaf(w, bfhi(v.x), acc[q * 8 + 1]);
    acc[q * 8 + 2] = fmaf(w, bflo(v.y), acc[q * 8 + 2]);
    acc[q * 8 + 3] = fmaf(w, bfhi(v.y), acc[q * 8 + 3]);
    acc[q * 8 + 4] = fmaf(w, bflo(v.z), acc[q * 8 + 4]);
    acc[q * 8 + 5] = fmaf(w, bfhi(v.z), acc[q * 8 + 5]);
    acc[q * 8 + 6] = fmaf(w, bflo(v.w), acc[q * 8 + 6]);
    acc[q * 8 + 7] = fmaf(w, bfhi(v.w), acc[q * 8 + 7]);
  }
}

template<int H, int C, int LPE, bool DOELU, bool FINAL>
__global__ __launch_bounds__(256) void k_agg(
    const int* __restrict__ rowptr2, const int* __restrict__ col,
    const float* __restrict__ ns, const float* __restrict__ nd,
    const unsigned short* __restrict__ xp, const float* __restrict__ bias,
    void* __restrict__ outp, const int* __restrict__ flag) {
  constexpr int HC = H * C;
  constexpr int CPL = HC / LPE;
  constexpr int EPW = 64 / LPE;
  int wave = threadIdx.x >> 6;
  int lane = threadIdx.x & 63;
  int n = blockIdx.x * 4 + wave;
  if (n >= NN) return;
  int rs = rowptr2[(size_t)n * WN];
  int deg = rowptr2[(size_t)n * WN + WN] - rs;
  int le = lane & (LPE - 1);   // lane within edge
  int eg = lane / LPE;         // edge group
  int ch0 = le * CPL;
  int h = (H == 1) ? 0 : (ch0 / C);
  float ndv = nd[n * H + h];
  const unsigned short* xpc = xp + ch0;
  float den = 0.f;
  float acc[CPL];
#pragma unroll
  for (int c = 0; c < CPL; ++c) acc[c] = 0.f;
  int j = eg;
  for (; j + EPW < deg; j += 2 * EPW) {
    int s0 = col[rs + j], s1 = col[rs + j + EPW];
    float l0 = ns[s0 * H + h] + ndv, l1 = ns[s1 * H + h] + ndv;
    l0 = l0 >= 0.f ? l0 : NEG * l0;
    l1 = l1 >= 0.f ? l1 : NEG * l1;
    float w0 = __expf(l0), w1 = __expf(l1);
    den += w0 + w1;
    const unsigned short* p0 = xpc + (size_t)s0 * HC;
    const unsigned short* p1 = xpc + (size_t)s1 * HC;
    accum<CPL>(w0, p0, acc);
    accum<CPL>(w1, p1, acc);
  }
  if (j < deg) {
    int s = col[rs + j];
    float l = ns[s * H + h] + ndv;
    l = l >= 0.f ? l : NEG * l;
    float w = __expf(l);
    den += w;
    accum<CPL>(w, xpc + (size_t)s * HC, acc);
  }
  // butterfly reduce across edge groups
#pragma unroll
  for (int off = 32; off >= LPE; off >>= 1) {
    den += __shfl_xor(den, off);
#pragma unroll
    for (int c = 0; c < CPL; ++c) acc[c] += __shfl_xor(acc[c], off);
  }
  if (eg != 0) return;
  float inv = 1.f / den;
  float o[CPL];
#pragma unroll
  for (int c = 0; c < CPL; ++c) {
    o[c] = acc[c] * inv + bias[ch0 + c];
    if (DOELU) o[c] = o[c] > 0.f ? o[c] : __expf(o[c]) - 1.f;
  }
  if (FINAL && !*flag) {
    float* op = (float*)outp + (size_t)n * HC + ch0;
#pragma unroll
    for (int q = 0; q < CPL / 4; ++q)
      *(float4*)(op + q * 4) = make_float4(o[q * 4], o[q * 4 + 1], o[q * 4 + 2], o[q * 4 + 3]);
  } else {
    unsigned short* op = (unsigned short*)outp + (size_t)n * HC + ch0;
#pragma unroll
    for (int q = 0; q < CPL / 8; ++q) {
      uint4 pk;
      pk.x = (unsigned)f2bfu(o[q * 8 + 0]) | ((unsigned)f2bfu(o[q * 8 + 1]) << 16);
      pk.y = (unsigned)f2bfu(o[q * 8 + 2]) | ((unsigned)f2bfu(o[q * 8 + 3]) << 16);
      pk.z = (unsigned)f2bfu(o[q * 8 + 4]) | ((unsigned)f2bfu(o[q * 8 + 5]) << 16);
      pk.w = (unsigned)f2bfu(o[q * 8 + 6]) | ((unsigned)f2bfu(o[q * 8 + 7]) << 16);
      *(uint4*)(op + q * 8) = pk;
    }
  }
}

extern "C" void kernel_launch(void* const* d_in, const int* in_sizes, int n_in,
                              void* d_out, int out_size, void* d_ws, size_t ws_size,
                              hipStream_t stream) {
  const void* x  = d_in[0];
  const int* ei  = (const int*)d_in[1];
  const void* W1 = d_in[2];
  const void* as1 = d_in[3];
  const void* ad1 = d_in[4];
  const void* b1 = d_in[5];
  const void* W2 = d_in[6];
  const void* as2 = d_in[7];
  const void* ad2 = d_in[8];
  const void* b2 = d_in[9];
  const int* srcs = ei;
  const int* dsts = ei + NE;

  char* w = (char*)d_ws;
  auto alloc = [&](size_t bytes) {
    char* p = w;
    w += (bytes + 255) & ~(size_t)255;
    return p;
  };
  int* flag   = (int*)alloc(4);
  unsigned short* hb  = (unsigned short*)alloc((size_t)NN * HC1 * 2);
  unsigned short* W1b = (unsigned short*)alloc((size_t)CIN * HC1 * 2);
  unsigned short* W2b = (unsigned short*)alloc((size_t)HC1 * C2 * 2);
  unsigned short* xp1 = (unsigned short*)alloc((size_t)NN * HC1 * 2);  // reused as xp2
  float* nAS1 = (float*)alloc((size_t)NN * H1 * 4);
  float* nAD1 = (float*)alloc((size_t)NN * H1 * 4);
  float* nAS2 = (float*)alloc((size_t)NN * 4);
  float* nAD2 = (float*)alloc((size_t)NN * 4);
  float* pAS1 = (float*)alloc((size_t)H1 * C1 * 4);
  float* pAD1 = (float*)alloc((size_t)H1 * C1 * 4);
  float* b1f  = (float*)alloc((size_t)HC1 * 4);
  float* pAS2 = (float*)alloc((size_t)C2 * 4);
  float* pAD2 = (float*)alloc((size_t)C2 * 4);
  float* b2f  = (float*)alloc((size_t)C2 * 4);
  int* rowptr2 = (int*)alloc(((size_t)NN * WN + 1) * 4);
  int* gcnt   = (int*)alloc((size_t)NB1 * SBLK * 4);
  int* bucketReal = (int*)alloc((size_t)NB1 * 4);
  int* sBase  = (int*)alloc((size_t)NB1 * 4);
  int* colx   = (int*)alloc((size_t)ET * 4);
  unsigned* staging = (unsigned*)alloc((size_t)NE * 4);
  unsigned short* xp2 = xp1;  // xp1 dead after layer-1 aggregation

  k_detect<<<1, 256, 0, stream>>>((const unsigned short*)x, flag);
  k_params<<<(CIN * HC1 + HC1 * C2 + HC1 + C2 + 255) / 256, 256, 0, stream>>>(
      W1, W2, as1, ad1, b1, as2, ad2, b2,
      W1b, W2b, pAS1, pAD1, b1f, pAS2, pAD2, b2f, flag);

  // ---- CSR build (dense counting sort, window-sub-sorted) ----
  k_histo<<<SBLK, 256, 0, stream>>>(dsts, gcnt);
  k_histscan<<<NB1, SBLK, 0, stream>>>(gcnt, bucketReal);
  k_base<<<1, 256, 0, stream>>>(bucketReal, sBase, rowptr2);
  k_scatter<<<SBLK, 256, 0, stream>>>(srcs, dsts, gcnt, sBase, staging);
  k_bucket2<<<NB1, 256, 0, stream>>>(staging, sBase, bucketReal, rowptr2, colx);

  int gb = (NN + 127) / 128;  // 782 blocks (4 waves x 32 rows)
  // ---- layer 1 ----
  k_gemm_mfma<8, H1, true><<<gb, 256, 0, stream>>>(
      x, W1b, xp1, pAS1, pAD1, nAS1, nAD1, NN, flag);
  k_agg<H1, C1, 8, true, false><<<(NN + 3) / 4, 256, 0, stream>>>(
      rowptr2, colx, nAS1, nAD1, xp1, b1f, hb, flag);

  // ---- layer 2 ----
  k_gemm_mfma<4, 1, false><<<gb, 256, 0, stream>>>(
      hb, W2b, xp2, pAS2, pAD2, nAS2, nAD2, NN, flag);
  k_agg<1, C2, 8, false, true><<<(NN + 3) / 4, 256, 0, stream>>>(
      rowptr2, colx, nAS2, nAD2, xp2, b2f, d_out, flag);
}